// Round 5
// baseline (433.119 us; speedup 1.0000x reference)
//
#include <hip/hip_runtime.h>
#include <math.h>

// Problem constants (from reference): D=256, DIN=512, F=16
#define DD 256
#define REPS 8   // replicated accumulators to reduce atomic same-address contention

// Workspace layout (float offsets)
#define OFF_SUMREP 0        // 2 inputs * REPS * 256 = 4096
#define OFF_H1P    4096     // 2 * 256 = 512   (pre-tanh partial sums, atomic target)
#define OFF_S1REP  4608     // 4096
#define OFF_H2P    8704     // 512
#define OFF_OREP   9216     // 4096
#define OFF_O      13312    // 512  (o1 then o2)
#define OFF_WTREP  13824    // REPS * 16 = 128
#define WS_FLOATS  13952

// Sweep geometry: 1024 co-resident blocks, flat grid-stride sliding window.
#define SWEEP_BLOCKS 1024
#define SWEEP_W ((size_t)SWEEP_BLOCKS * 256)   // float4 stride per step

typedef float f32x4 __attribute__((ext_vector_type(4)));

__device__ __forceinline__ float sigmoidf_(float x) { return 1.0f / (1.0f + __expf(-x)); }
__device__ __forceinline__ float dot4(f32x4 a, f32x4 b) {
    return a.x * b.x + a.y * b.y + a.z * b.z + a.w * b.w;
}
__device__ __forceinline__ f32x4 tanh4(f32x4 a) {
    f32x4 r; r.x = tanhf(a.x); r.y = tanhf(a.y); r.z = tanhf(a.z); r.w = tanhf(a.w);
    return r;
}
__device__ __forceinline__ float wave_sum(float v) {
#pragma unroll
    for (int off = 32; off; off >>= 1) v += __shfl_xor(v, off, 64);
    return v;
}

__global__ void k_zero(float* __restrict__ ws) {
    int i = blockIdx.x * 256 + threadIdx.x;
    if (i < WS_FLOATS) ws[i] = 0.0f;
}

// Block-level f32x4 reduce of 4 waves + replicated atomic finish.
__device__ __forceinline__ void block_reduce_atomic(f32x4 acc, int t, float* dst_base,
                                                    f32x4* lds) {
    lds[t] = acc;
    __syncthreads();
    if (t < 64) {
        f32x4 s = lds[t] + lds[t + 64] + lds[t + 128] + lds[t + 192];
        float* dst = dst_base + t * 4;
        atomicAdd(dst + 0, s.x); atomicAdd(dst + 1, s.y);
        atomicAdd(dst + 2, s.z); atomicAdd(dst + 3, s.w);
    }
    __syncthreads();
}

// Pass A: column sums of x1 then x2, machine-wide sliding window.
__global__ void __launch_bounds__(256, 4)
k_mean(const float* __restrict__ x1, const float* __restrict__ x2,
       int N1, int N2, float* __restrict__ ws) {
    int t = threadIdx.x;
    size_t idx = (size_t)blockIdx.x * 256 + t;
    const f32x4* p1 = (const f32x4*)x1;
    const f32x4* p2 = (const f32x4*)x2;
    size_t end1 = (size_t)N1 * 64, end2 = (size_t)N2 * 64;
    f32x4 a = {0.f, 0.f, 0.f, 0.f}, b = a;
    size_t i = idx;
    for (; i + 3 * SWEEP_W < end1; i += 4 * SWEEP_W) {
        f32x4 v0 = p1[i], v1 = p1[i + SWEEP_W], v2 = p1[i + 2 * SWEEP_W], v3 = p1[i + 3 * SWEEP_W];
        a += (v0 + v1) + (v2 + v3);
    }
    for (; i < end1; i += SWEEP_W) a += p1[i];
    i = idx;
    for (; i + 3 * SWEEP_W < end2; i += 4 * SWEEP_W) {
        f32x4 v0 = p2[i], v1 = p2[i + SWEEP_W], v2 = p2[i + 2 * SWEEP_W], v3 = p2[i + 3 * SWEEP_W];
        b += (v0 + v1) + (v2 + v3);
    }
    for (; i < end2; i += SWEEP_W) b += p2[i];
    __shared__ f32x4 lds[256];
    int rep = blockIdx.x & (REPS - 1);
    block_reduce_atomic(a, t, ws + OFF_SUMREP + rep * 256, lds);
    block_reduce_atomic(b, t, ws + OFF_SUMREP + (REPS + rep) * 256, lds);
}

// hP[inp] += partial of (colsum/N) @ W0 over a 16-row slice of W0.
__global__ void k_hpart(const float* __restrict__ W0, float* __restrict__ ws,
                        int srcOff, int dstOff, int N1, int N2) {
    int inp = blockIdx.x >> 4, g = blockIdx.x & 15;
    int t = threadIdx.x;
    __shared__ float temp[16];
    if (t < 16) {
        const float* src = ws + srcOff + inp * (REPS * 256) + g * 16 + t;
        float s = 0.f;
#pragma unroll
        for (int r = 0; r < REPS; r++) s += src[r * 256];
        temp[t] = s * (1.0f / (float)(inp ? N2 : N1));
    }
    __syncthreads();
    float p = 0.f;
#pragma unroll
    for (int j = 0; j < 16; j++) p += temp[j] * W0[(g * 16 + j) * 256 + t];
    atomicAdd(ws + dstOff + inp * 256 + t, p);
}

// Pass B: s1 = sum_i sigmoid(x_i . h1) * x_i, both inputs, sliding window.
__global__ void __launch_bounds__(256, 4)
k_att1(const float* __restrict__ x1, const float* __restrict__ x2,
       int N1, int N2, float* __restrict__ ws) {
    int t = threadIdx.x;
    int lane = t & 63;
    size_t idx = (size_t)blockIdx.x * 256 + t;
    const f32x4* p1 = (const f32x4*)x1;
    const f32x4* p2 = (const f32x4*)x2;
    size_t end1 = (size_t)N1 * 64, end2 = (size_t)N2 * 64;
    f32x4 hA = tanh4(((const f32x4*)(ws + OFF_H1P))[lane]);         // inp 0
    f32x4 hB = tanh4(((const f32x4*)(ws + OFF_H1P + 256))[lane]);   // inp 1
    f32x4 accA = {0.f, 0.f, 0.f, 0.f}, accB = accA;
    size_t i = idx;
    for (; i + SWEEP_W < end1; i += 2 * SWEEP_W) {
        f32x4 v0 = p1[i], v1 = p1[i + SWEEP_W];
        float d0 = dot4(v0, hA), d1 = dot4(v1, hA);
#pragma unroll
        for (int off = 32; off; off >>= 1) {
            d0 += __shfl_xor(d0, off, 64); d1 += __shfl_xor(d1, off, 64);
        }
        accA += sigmoidf_(d0) * v0 + sigmoidf_(d1) * v1;
    }
    for (; i < end1; i += SWEEP_W) {
        f32x4 v = p1[i];
        accA += sigmoidf_(wave_sum(dot4(v, hA))) * v;
    }
    i = idx;
    for (; i + SWEEP_W < end2; i += 2 * SWEEP_W) {
        f32x4 v0 = p2[i], v1 = p2[i + SWEEP_W];
        float d0 = dot4(v0, hB), d1 = dot4(v1, hB);
#pragma unroll
        for (int off = 32; off; off >>= 1) {
            d0 += __shfl_xor(d0, off, 64); d1 += __shfl_xor(d1, off, 64);
        }
        accB += sigmoidf_(d0) * v0 + sigmoidf_(d1) * v1;
    }
    for (; i < end2; i += SWEEP_W) {
        f32x4 v = p2[i];
        accB += sigmoidf_(wave_sum(dot4(v, hB))) * v;
    }
    __shared__ f32x4 lds[256];
    int rep = blockIdx.x & (REPS - 1);
    block_reduce_atomic(accA, t, ws + OFF_S1REP + rep * 256, lds);
    block_reduce_atomic(accB, t, ws + OFF_S1REP + (REPS + rep) * 256, lds);
}

// Pass C: o = sum_i att1_i*att2_i*x_i, att2_i = sigmoid(att1_i * (x_i . h2)).
__global__ void __launch_bounds__(256, 4)
k_att2(const float* __restrict__ x1, const float* __restrict__ x2,
       int N1, int N2, float* __restrict__ ws) {
    int t = threadIdx.x;
    int lane = t & 63;
    size_t idx = (size_t)blockIdx.x * 256 + t;
    const f32x4* p1 = (const f32x4*)x1;
    const f32x4* p2 = (const f32x4*)x2;
    size_t end1 = (size_t)N1 * 64, end2 = (size_t)N2 * 64;
    f32x4 h1A = tanh4(((const f32x4*)(ws + OFF_H1P))[lane]);
    f32x4 h1B = tanh4(((const f32x4*)(ws + OFF_H1P + 256))[lane]);
    f32x4 h2A = tanh4(((const f32x4*)(ws + OFF_H2P))[lane]);
    f32x4 h2B = tanh4(((const f32x4*)(ws + OFF_H2P + 256))[lane]);
    f32x4 accA = {0.f, 0.f, 0.f, 0.f}, accB = accA;
    size_t i = idx;
    for (; i + SWEEP_W < end1; i += 2 * SWEEP_W) {
        f32x4 v0 = p1[i], v1 = p1[i + SWEEP_W];
        float d0 = dot4(v0, h1A), d1 = dot4(v1, h1A);
        float e0 = dot4(v0, h2A), e1 = dot4(v1, h2A);
#pragma unroll
        for (int off = 32; off; off >>= 1) {
            d0 += __shfl_xor(d0, off, 64); e0 += __shfl_xor(e0, off, 64);
            d1 += __shfl_xor(d1, off, 64); e1 += __shfl_xor(e1, off, 64);
        }
        float a0 = sigmoidf_(d0), a1 = sigmoidf_(d1);
        accA += (a0 * sigmoidf_(a0 * e0)) * v0 + (a1 * sigmoidf_(a1 * e1)) * v1;
    }
    for (; i < end1; i += SWEEP_W) {
        f32x4 v = p1[i];
        float d = dot4(v, h1A), e = dot4(v, h2A);
#pragma unroll
        for (int off = 32; off; off >>= 1) {
            d += __shfl_xor(d, off, 64); e += __shfl_xor(e, off, 64);
        }
        float a1 = sigmoidf_(d);
        accA += (a1 * sigmoidf_(a1 * e)) * v;
    }
    i = idx;
    for (; i + SWEEP_W < end2; i += 2 * SWEEP_W) {
        f32x4 v0 = p2[i], v1 = p2[i + SWEEP_W];
        float d0 = dot4(v0, h1B), d1 = dot4(v1, h1B);
        float e0 = dot4(v0, h2B), e1 = dot4(v1, h2B);
#pragma unroll
        for (int off = 32; off; off >>= 1) {
            d0 += __shfl_xor(d0, off, 64); e0 += __shfl_xor(e0, off, 64);
            d1 += __shfl_xor(d1, off, 64); e1 += __shfl_xor(e1, off, 64);
        }
        float a0 = sigmoidf_(d0), a1 = sigmoidf_(d1);
        accB += (a0 * sigmoidf_(a0 * e0)) * v0 + (a1 * sigmoidf_(a1 * e1)) * v1;
    }
    for (; i < end2; i += SWEEP_W) {
        f32x4 v = p2[i];
        float d = dot4(v, h1B), e = dot4(v, h2B);
#pragma unroll
        for (int off = 32; off; off >>= 1) {
            d += __shfl_xor(d, off, 64); e += __shfl_xor(e, off, 64);
        }
        float a1 = sigmoidf_(d);
        accB += (a1 * sigmoidf_(a1 * e)) * v;
    }
    __shared__ f32x4 lds[256];
    int rep = blockIdx.x & (REPS - 1);
    block_reduce_atomic(accA, t, ws + OFF_OREP + rep * 256, lds);
    block_reduce_atomic(accB, t, ws + OFF_OREP + (REPS + rep) * 256, lds);
}

// Combine o replicas -> o1[256], o2[256]
__global__ void k_comb(float* __restrict__ ws) {
    int t = threadIdx.x;           // 512 threads
    int inp = t >> 8, c = t & 255;
    float s = 0.f;
#pragma unroll
    for (int r = 0; r < REPS; r++) s += ws[OFF_OREP + inp * (REPS * 256) + r * 256 + c];
    ws[OFF_O + t] = s;
}

// w_term[f] = sum_{d,e} g1[d] W[f,d,e] g2[e], g=[o,o] duplication folded.
// 8192 rows (f,d) of 512 floats, flat grid-stride: wave g -> rows g, g+2048, ...
__global__ void __launch_bounds__(256, 4)
k_ntn(const float* __restrict__ W, float* __restrict__ ws) {
    int b = blockIdx.x, t = threadIdx.x;
    int lane = t & 63, w = t >> 6;
    const float* o1 = ws + OFF_O;
    f32x4 o2f = ((const f32x4*)(ws + OFF_O + 256))[lane];
    int g = b * 4 + w;              // global wave id, 2048 waves
    const f32x4* W4 = (const f32x4*)W;
    float wt[4];
    int fidx[4];
#pragma unroll
    for (int u = 0; u < 4; u++) {
        int row = g + u * 2048;     // (f,d) flat
        const f32x4* q = W4 + (size_t)row * 128 + lane;
        f32x4 a = q[0], c = q[64];
        float p = dot4(a + c, o2f);
        p = wave_sum(p);
        wt[u] = o1[row & 255] * p;  // d&255 == row&255 since 512|row-stride
        fidx[u] = row >> 9;
    }
    if (lane == 0) {
        float* dst = ws + OFF_WTREP + (b & (REPS - 1)) * 16;
#pragma unroll
        for (int u = 0; u < 4; u++) atomicAdd(dst + fidx[u], wt[u]);
    }
}

// v_term + w_term + b -> sigmoid -> 4-layer MLP -> out[0]
__global__ void k_final(const float* __restrict__ V, const float* __restrict__ bb,
                        const float* __restrict__ P0, const float* __restrict__ P1,
                        const float* __restrict__ P2, const float* __restrict__ P3,
                        float* __restrict__ ws, float* __restrict__ out) {
    int t = threadIdx.x;           // 256 threads
    const float* o = ws + OFF_O;
    int f = t >> 4, j = t & 15;
    float p = 0.f;
    for (int k = j; k < 1024; k += 16) {
        float cv = (k < 512) ? o[k & 255] : o[256 + (k & 255)];
        p += cv * V[f * 1024 + k];
    }
    __shared__ float red[256];
    __shared__ float sv[16];
    red[t] = p;
    __syncthreads();
    if (t < 16) {
        float v = 0.f;
#pragma unroll
        for (int q = 0; q < 16; q++) v += red[t * 16 + q];
        float wt = 0.f;
#pragma unroll
        for (int r = 0; r < REPS; r++) wt += ws[OFF_WTREP + r * 16 + t];
        sv[t] = sigmoidf_(v + wt + bb[t]);
    }
    __syncthreads();
    if (t == 0) {
        float y0[8], y1[4], y2[2];
#pragma unroll
        for (int i = 0; i < 8; i++) {
            float s = 0.f;
            for (int k = 0; k < 16; k++) s += P0[i * 16 + k] * sv[k];
            y0[i] = sigmoidf_(s);
        }
#pragma unroll
        for (int i = 0; i < 4; i++) {
            float s = 0.f;
            for (int k = 0; k < 8; k++) s += P1[i * 8 + k] * y0[k];
            y1[i] = sigmoidf_(s);
        }
#pragma unroll
        for (int i = 0; i < 2; i++) {
            float s = 0.f;
            for (int k = 0; k < 4; k++) s += P2[i * 4 + k] * y1[k];
            y2[i] = sigmoidf_(s);
        }
        out[0] = sigmoidf_(P3[0] * y2[0] + P3[1] * y2[1]);
    }
}

extern "C" void kernel_launch(void* const* d_in, const int* in_sizes, int n_in,
                              void* d_out, int out_size, void* d_ws, size_t ws_size,
                              hipStream_t stream) {
    const float* x1 = (const float*)d_in[0];
    const float* x2 = (const float*)d_in[1];
    const float* W0 = (const float*)d_in[2];
    const float* V  = (const float*)d_in[3];
    const float* W  = (const float*)d_in[4];
    const float* b  = (const float*)d_in[5];
    const float* P0 = (const float*)d_in[6];
    const float* P1 = (const float*)d_in[7];
    const float* P2 = (const float*)d_in[8];
    const float* P3 = (const float*)d_in[9];
    float* ws  = (float*)d_ws;
    float* out = (float*)d_out;
    int N1 = in_sizes[0] / DD;   // 120000
    int N2 = in_sizes[1] / DD;   // 100000

    k_zero  <<<55,           256, 0, stream>>>(ws);
    k_mean  <<<SWEEP_BLOCKS, 256, 0, stream>>>(x1, x2, N1, N2, ws);
    k_hpart <<<32,           256, 0, stream>>>(W0, ws, OFF_SUMREP, OFF_H1P, N1, N2);
    k_att1  <<<SWEEP_BLOCKS, 256, 0, stream>>>(x1, x2, N1, N2, ws);
    k_hpart <<<32,           256, 0, stream>>>(W0, ws, OFF_S1REP, OFF_H2P, N1, N2);
    k_att2  <<<SWEEP_BLOCKS, 256, 0, stream>>>(x1, x2, N1, N2, ws);
    k_comb  <<<1,            512, 0, stream>>>(ws);
    k_ntn   <<<512,          256, 0, stream>>>(W, ws);
    k_final <<<1,            256, 0, stream>>>(V, b, P0, P1, P2, P3, ws, out);
}

// Round 6
// 423.978 us; speedup vs baseline: 1.0216x; 1.0216x over previous
//
#include <hip/hip_runtime.h>
#include <math.h>

// Problem constants (from reference): D=256, DIN=512, F=16
#define DD 256
#define REPS 8   // replicated accumulators to reduce atomic same-address contention

// Workspace layout (float offsets) for the small stats region
#define OFF_SUMREP 0        // 2 inputs * REPS * 256 = 4096
#define OFF_H1P    4096     // 2 * 256 = 512   (pre-tanh partial sums, atomic target)
#define OFF_S1REP  4608     // 4096
#define OFF_H2P    8704     // 512
#define OFF_OREP   9216     // 4096
#define OFF_WTREP  13824    // REPS * 16 = 128
#define WS_FLOATS  13952
#define MIRROR_OFF_BYTES 65536   // fp16 mirror of x1,x2 starts here

typedef float    f32x4 __attribute__((ext_vector_type(4)));
typedef _Float16 f16x4 __attribute__((ext_vector_type(4)));

__device__ __forceinline__ float sigmoidf_(float x) { return 1.0f / (1.0f + __expf(-x)); }
__device__ __forceinline__ float dot4(f32x4 a, f32x4 b) {
    return a.x * b.x + a.y * b.y + a.z * b.z + a.w * b.w;
}
__device__ __forceinline__ f32x4 tanh4(f32x4 a) {
    f32x4 r; r.x = tanhf(a.x); r.y = tanhf(a.y); r.z = tanhf(a.z); r.w = tanhf(a.w);
    return r;
}
__device__ __forceinline__ float wave_sum(float v) {
#pragma unroll
    for (int off = 32; off; off >>= 1) v += __shfl_xor(v, off, 64);
    return v;
}
// load-row abstraction: fp32 direct or fp16 mirror (convert to fp32)
__device__ __forceinline__ f32x4 ld4(const f32x4* p, size_t i) { return p[i]; }
__device__ __forceinline__ f32x4 ld4(const f16x4* p, size_t i) {
    return __builtin_convertvector(p[i], f32x4);
}

__global__ void k_zero(float* __restrict__ ws) {
    int i = blockIdx.x * 256 + threadIdx.x;
    if (i < WS_FLOATS) ws[i] = 0.0f;
}

// Block-level f32x4 reduce of 4 waves + replicated atomic finish.
__device__ __forceinline__ void block_reduce_atomic(f32x4 acc, int t, float* dst_base,
                                                    f32x4* lds) {
    lds[t] = acc;
    __syncthreads();
    if (t < 64) {
        f32x4 s = lds[t] + lds[t + 64] + lds[t + 128] + lds[t + 192];
        float* dst = dst_base + t * 4;
        atomicAdd(dst + 0, s.x); atomicAdd(dst + 1, s.y);
        atomicAdd(dst + 2, s.z); atomicAdd(dst + 3, s.w);
    }
}

// Pass A: column sums of fp32 x (+ optional fp16 mirror write).
// Split grid: [0,1024)->x1, [1024,2048)->x2; contiguous chunk per block; wave-per-row.
template<bool WM>
__global__ void __launch_bounds__(256, 4)
k_mean_t(const f32x4* __restrict__ x1, const f32x4* __restrict__ x2,
         f16x4* __restrict__ m1, f16x4* __restrict__ m2,
         int N1, int N2, float* __restrict__ ws) {
    int b = blockIdx.x, t = threadIdx.x;
    int inp = b >> 10, bl = b & 1023;
    const f32x4* x = inp ? x2 : x1;
    f16x4* mm = inp ? m2 : m1;
    int N = inp ? N2 : N1;
    int chunk = (N + 1023) >> 10;
    int start = bl * chunk, end = min(start + chunk, N);
    int lane = t & 63, w = t >> 6;
    f32x4 a0 = {0.f, 0.f, 0.f, 0.f}, a1 = a0;
    int r = start + w;
    for (; r + 12 < end; r += 16) {
        size_t i0 = (size_t)r * 64 + lane;
        f32x4 v0 = x[i0], v1 = x[i0 + 256], v2 = x[i0 + 512], v3 = x[i0 + 768];
        if (WM) {
            mm[i0]       = __builtin_convertvector(v0, f16x4);
            mm[i0 + 256] = __builtin_convertvector(v1, f16x4);
            mm[i0 + 512] = __builtin_convertvector(v2, f16x4);
            mm[i0 + 768] = __builtin_convertvector(v3, f16x4);
        }
        a0 += v0 + v1; a1 += v2 + v3;
    }
    for (; r < end; r += 4) {
        size_t i0 = (size_t)r * 64 + lane;
        f32x4 v = x[i0];
        if (WM) mm[i0] = __builtin_convertvector(v, f16x4);
        a0 += v;
    }
    a0 += a1;
    __shared__ f32x4 lds[256];
    block_reduce_atomic(a0, t, ws + OFF_SUMREP + inp * (REPS * 256) + (bl & (REPS - 1)) * 256, lds);
}

// hP[inp] += partial of (colsum/N) @ W0 over a 16-row slice of W0.
__global__ void k_hpart(const float* __restrict__ W0, float* __restrict__ ws,
                        int srcOff, int dstOff, int N1, int N2) {
    int inp = blockIdx.x >> 4, g = blockIdx.x & 15;
    int t = threadIdx.x;
    __shared__ float temp[16];
    if (t < 16) {
        const float* src = ws + srcOff + inp * (REPS * 256) + g * 16 + t;
        float s = 0.f;
#pragma unroll
        for (int r = 0; r < REPS; r++) s += src[r * 256];
        temp[t] = s * (1.0f / (float)(inp ? N2 : N1));
    }
    __syncthreads();
    float p = 0.f;
#pragma unroll
    for (int j = 0; j < 16; j++) p += temp[j] * W0[(g * 16 + j) * 256 + t];
    atomicAdd(ws + dstOff + inp * 256 + t, p);
}

// Pass B: s1 = sum_i sigmoid(x_i . h1) * x_i.  T = f16x4 (mirror) or f32x4 (fallback).
template<typename T>
__global__ void __launch_bounds__(256, 4)
k_att1_t(const T* __restrict__ b1, const T* __restrict__ b2,
         int N1, int N2, float* __restrict__ ws) {
    int b = blockIdx.x, t = threadIdx.x;
    int inp = b >> 10, bl = b & 1023;
    const T* x = inp ? b2 : b1;
    int N = inp ? N2 : N1;
    int chunk = (N + 1023) >> 10;
    int start = bl * chunk, end = min(start + chunk, N);
    int lane = t & 63, w = t >> 6;
    f32x4 h1 = tanh4(((const f32x4*)(ws + OFF_H1P + inp * 256))[lane]);
    f32x4 acc = {0.f, 0.f, 0.f, 0.f};
    int r = start + w;
    for (; r + 12 < end; r += 16) {
        size_t i0 = (size_t)r * 64 + lane;
        f32x4 v0 = ld4(x, i0), v1 = ld4(x, i0 + 256), v2 = ld4(x, i0 + 512), v3 = ld4(x, i0 + 768);
        float d0 = dot4(v0, h1), d1 = dot4(v1, h1), d2 = dot4(v2, h1), d3 = dot4(v3, h1);
#pragma unroll
        for (int off = 32; off; off >>= 1) {
            d0 += __shfl_xor(d0, off, 64); d1 += __shfl_xor(d1, off, 64);
            d2 += __shfl_xor(d2, off, 64); d3 += __shfl_xor(d3, off, 64);
        }
        acc += sigmoidf_(d0) * v0 + sigmoidf_(d1) * v1;
        acc += sigmoidf_(d2) * v2 + sigmoidf_(d3) * v3;
    }
    for (; r < end; r += 4) {
        f32x4 v = ld4(x, (size_t)r * 64 + lane);
        acc += sigmoidf_(wave_sum(dot4(v, h1))) * v;
    }
    __shared__ f32x4 lds[256];
    block_reduce_atomic(acc, t, ws + OFF_S1REP + inp * (REPS * 256) + (bl & (REPS - 1)) * 256, lds);
}

// Pass C: o = sum_i att1_i*att2_i*x_i, att2_i = sigmoid(att1_i * (x_i . h2)).
template<typename T>
__global__ void __launch_bounds__(256, 4)
k_att2_t(const T* __restrict__ b1, const T* __restrict__ b2,
         int N1, int N2, float* __restrict__ ws) {
    int b = blockIdx.x, t = threadIdx.x;
    int inp = b >> 10, bl = b & 1023;
    const T* x = inp ? b2 : b1;
    int N = inp ? N2 : N1;
    int chunk = (N + 1023) >> 10;
    int start = bl * chunk, end = min(start + chunk, N);
    int lane = t & 63, w = t >> 6;
    f32x4 h1 = tanh4(((const f32x4*)(ws + OFF_H1P + inp * 256))[lane]);
    f32x4 h2 = tanh4(((const f32x4*)(ws + OFF_H2P + inp * 256))[lane]);
    f32x4 acc = {0.f, 0.f, 0.f, 0.f};
    int r = start + w;
    for (; r + 4 < end; r += 8) {
        size_t i0 = (size_t)r * 64 + lane;
        f32x4 v0 = ld4(x, i0), v1 = ld4(x, i0 + 256);
        float d0 = dot4(v0, h1), d1 = dot4(v1, h1);
        float e0 = dot4(v0, h2), e1 = dot4(v1, h2);
#pragma unroll
        for (int off = 32; off; off >>= 1) {
            d0 += __shfl_xor(d0, off, 64); e0 += __shfl_xor(e0, off, 64);
            d1 += __shfl_xor(d1, off, 64); e1 += __shfl_xor(e1, off, 64);
        }
        float a0 = sigmoidf_(d0), a1 = sigmoidf_(d1);
        acc += (a0 * sigmoidf_(a0 * e0)) * v0 + (a1 * sigmoidf_(a1 * e1)) * v1;
    }
    for (; r < end; r += 4) {
        f32x4 v = ld4(x, (size_t)r * 64 + lane);
        float d = dot4(v, h1), e = dot4(v, h2);
#pragma unroll
        for (int off = 32; off; off >>= 1) {
            d += __shfl_xor(d, off, 64); e += __shfl_xor(e, off, 64);
        }
        float a1 = sigmoidf_(d);
        acc += (a1 * sigmoidf_(a1 * e)) * v;
    }
    __shared__ f32x4 lds[256];
    block_reduce_atomic(acc, t, ws + OFF_OREP + inp * (REPS * 256) + (bl & (REPS - 1)) * 256, lds);
}

// w_term[f] = g1.W[f].g2 with g=[o,o] folded; o recombined from OREP in-block.
__global__ void __launch_bounds__(256, 4)
k_ntn(const float* __restrict__ W, float* __restrict__ ws) {
    __shared__ __align__(16) float o_l[512];
    int b = blockIdx.x, t = threadIdx.x;
    {
        float s0 = 0.f, s1 = 0.f;
#pragma unroll
        for (int r2 = 0; r2 < REPS; r2++) {
            s0 += ws[OFF_OREP + r2 * 256 + t];
            s1 += ws[OFF_OREP + REPS * 256 + r2 * 256 + t];
        }
        o_l[t] = s0; o_l[256 + t] = s1;
    }
    __syncthreads();
    int lane = t & 63, w = t >> 6;
    f32x4 o2f = ((const f32x4*)(o_l + 256))[lane];
    int g = b * 4 + w;              // global wave id, 2048 waves
    const f32x4* W4 = (const f32x4*)W;
    float wt[4];
    int fidx[4];
#pragma unroll
    for (int u = 0; u < 4; u++) {
        int row = g + u * 2048;     // (f,d) flat, 8192 rows
        const f32x4* q = W4 + (size_t)row * 128 + lane;
        float p = wave_sum(dot4(q[0] + q[64], o2f));
        wt[u] = o_l[row & 255] * p;
        fidx[u] = row >> 9;
    }
    if (lane == 0) {
        float* dst = ws + OFF_WTREP + (b & (REPS - 1)) * 16;
#pragma unroll
        for (int u = 0; u < 4; u++) atomicAdd(dst + fidx[u], wt[u]);
    }
}

// v_term + w_term + b -> sigmoid -> 4-layer MLP -> out[0]. o recombined in-block.
__global__ void k_final(const float* __restrict__ V, const float* __restrict__ bb,
                        const float* __restrict__ P0, const float* __restrict__ P1,
                        const float* __restrict__ P2, const float* __restrict__ P3,
                        float* __restrict__ ws, float* __restrict__ out) {
    int t = threadIdx.x;           // 256 threads
    __shared__ float o_l[512];
    {
        float s0 = 0.f, s1 = 0.f;
#pragma unroll
        for (int r2 = 0; r2 < REPS; r2++) {
            s0 += ws[OFF_OREP + r2 * 256 + t];
            s1 += ws[OFF_OREP + REPS * 256 + r2 * 256 + t];
        }
        o_l[t] = s0; o_l[256 + t] = s1;
    }
    __syncthreads();
    int f = t >> 4, j = t & 15;
    float p = 0.f;
    for (int k = j; k < 1024; k += 16) {
        float cv = (k < 512) ? o_l[k & 255] : o_l[256 + (k & 255)];
        p += cv * V[f * 1024 + k];
    }
    __shared__ float red[256];
    __shared__ float sv[16];
    red[t] = p;
    __syncthreads();
    if (t < 16) {
        float v = 0.f;
#pragma unroll
        for (int q = 0; q < 16; q++) v += red[t * 16 + q];
        float wt = 0.f;
#pragma unroll
        for (int r = 0; r < REPS; r++) wt += ws[OFF_WTREP + r * 16 + t];
        sv[t] = sigmoidf_(v + wt + bb[t]);
    }
    __syncthreads();
    if (t == 0) {
        float y0[8], y1[4], y2[2];
#pragma unroll
        for (int i = 0; i < 8; i++) {
            float s = 0.f;
            for (int k = 0; k < 16; k++) s += P0[i * 16 + k] * sv[k];
            y0[i] = sigmoidf_(s);
        }
#pragma unroll
        for (int i = 0; i < 4; i++) {
            float s = 0.f;
            for (int k = 0; k < 8; k++) s += P1[i * 8 + k] * y0[k];
            y1[i] = sigmoidf_(s);
        }
#pragma unroll
        for (int i = 0; i < 2; i++) {
            float s = 0.f;
            for (int k = 0; k < 4; k++) s += P2[i * 4 + k] * y1[k];
            y2[i] = sigmoidf_(s);
        }
        out[0] = sigmoidf_(P3[0] * y2[0] + P3[1] * y2[1]);
    }
}

extern "C" void kernel_launch(void* const* d_in, const int* in_sizes, int n_in,
                              void* d_out, int out_size, void* d_ws, size_t ws_size,
                              hipStream_t stream) {
    const float* x1 = (const float*)d_in[0];
    const float* x2 = (const float*)d_in[1];
    const float* W0 = (const float*)d_in[2];
    const float* V  = (const float*)d_in[3];
    const float* W  = (const float*)d_in[4];
    const float* b  = (const float*)d_in[5];
    const float* P0 = (const float*)d_in[6];
    const float* P1 = (const float*)d_in[7];
    const float* P2 = (const float*)d_in[8];
    const float* P3 = (const float*)d_in[9];
    float* ws  = (float*)d_ws;
    float* out = (float*)d_out;
    int N1 = in_sizes[0] / DD;   // 120000
    int N2 = in_sizes[1] / DD;   // 100000

    const f32x4* x1v = (const f32x4*)x1;
    const f32x4* x2v = (const f32x4*)x2;
    f16x4* m1 = (f16x4*)((char*)d_ws + MIRROR_OFF_BYTES);
    f16x4* m2 = m1 + (size_t)N1 * 64;
    size_t need = (size_t)MIRROR_OFF_BYTES + ((size_t)N1 + N2) * DD * sizeof(_Float16);
    bool use_mirror = ws_size >= need;

    k_zero <<<55, 256, 0, stream>>>(ws);
    if (use_mirror) {
        k_mean_t<true>  <<<2048, 256, 0, stream>>>(x1v, x2v, m1, m2, N1, N2, ws);
        k_hpart         <<<32,   256, 0, stream>>>(W0, ws, OFF_SUMREP, OFF_H1P, N1, N2);
        k_att1_t<f16x4> <<<2048, 256, 0, stream>>>(m1, m2, N1, N2, ws);
        k_hpart         <<<32,   256, 0, stream>>>(W0, ws, OFF_S1REP, OFF_H2P, N1, N2);
        k_att2_t<f16x4> <<<2048, 256, 0, stream>>>(m1, m2, N1, N2, ws);
    } else {
        k_mean_t<false> <<<2048, 256, 0, stream>>>(x1v, x2v, nullptr, nullptr, N1, N2, ws);
        k_hpart         <<<32,   256, 0, stream>>>(W0, ws, OFF_SUMREP, OFF_H1P, N1, N2);
        k_att1_t<f32x4> <<<2048, 256, 0, stream>>>(x1v, x2v, N1, N2, ws);
        k_hpart         <<<32,   256, 0, stream>>>(W0, ws, OFF_S1REP, OFF_H2P, N1, N2);
        k_att2_t<f32x4> <<<2048, 256, 0, stream>>>(x1v, x2v, N1, N2, ws);
    }
    k_ntn  <<<512, 256, 0, stream>>>(W, ws);
    k_final<<<1,   256, 0, stream>>>(V, b, P0, P1, P2, P3, ws, out);
}

// Round 7
// 406.245 us; speedup vs baseline: 1.0662x; 1.0437x over previous
//
#include <hip/hip_runtime.h>
#include <math.h>

// Problem constants (from reference): D=256, DIN=512, F=16
#define DD 256
#define REPS 8   // replicated accumulators to reduce atomic same-address contention

// Workspace layout (float offsets) for the small stats region
#define OFF_SUMREP 0        // 2 inputs * REPS * 256 = 4096
#define OFF_H1P    4096     // 2 * 256 = 512   (pre-tanh partial sums, atomic target)
#define OFF_S1REP  4608     // 4096
#define OFF_H2P    8704     // 512
#define OFF_OREP   9216     // 4096
#define OFF_WTREP  13824    // REPS * 16 = 128
#define WS_FLOATS  13952
#define MIRROR_OFF_BYTES 65536   // fp16 mirror of x1,x2 starts here

typedef float    f32x4 __attribute__((ext_vector_type(4)));
typedef float    f32x8 __attribute__((ext_vector_type(8)));
typedef _Float16 f16x4 __attribute__((ext_vector_type(4)));
typedef _Float16 f16x8 __attribute__((ext_vector_type(8)));

__device__ __forceinline__ float sigmoidf_(float x) { return 1.0f / (1.0f + __expf(-x)); }

// row-of-8 loaders: fp16 mirror (convert) or raw fp32 (fallback)
__device__ __forceinline__ f32x8 ld8(const f16x8* p, size_t i) {
    return __builtin_convertvector(p[i], f32x8);
}
__device__ __forceinline__ f32x8 ld8(const f32x8* p, size_t i) { return p[i]; }

__device__ __forceinline__ float dot8(f32x8 a, f32x8 b) {
    f32x8 m = a * b;
    return ((m[0] + m[4]) + (m[1] + m[5])) + ((m[2] + m[6]) + (m[3] + m[7]));
}

__global__ void k_zero(float* __restrict__ ws) {
    int i = blockIdx.x * 256 + threadIdx.x;
    if (i < WS_FLOATS) ws[i] = 0.0f;
}

// f32x4 block reduce (4 waves) + replicated atomic finish (for k_mean).
__device__ __forceinline__ void block_reduce_atomic4(f32x4 acc, int t, float* dst_base) {
    __shared__ f32x4 lds[256];
    lds[t] = acc;
    __syncthreads();
    if (t < 64) {
        f32x4 s = lds[t] + lds[t + 64] + lds[t + 128] + lds[t + 192];
        float* dst = dst_base + t * 4;
        atomicAdd(dst + 0, s.x); atomicAdd(dst + 1, s.y);
        atomicAdd(dst + 2, s.z); atomicAdd(dst + 3, s.w);
    }
}

// f32x8 block reduce (8 half-wave slots) + replicated atomic finish (att kernels).
__device__ __forceinline__ void block_reduce_atomic8(f32x8 acc, int t, float* dst_base) {
    __shared__ f32x8 lds8[256];
    lds8[t] = acc;
    __syncthreads();
    const float* lf = (const float*)lds8;
    float s = 0.f;
#pragma unroll
    for (int slot = 0; slot < 8; slot++) s += lf[slot * 256 + t];   // conflict-free
    atomicAdd(dst_base + t, s);
}

// Pass A (R1 geometry): column sums + optional fp16 mirror write.
// Grid 1024: [0,512)->x1, [512,1024)->x2; wave-per-row, stride 2048 rows.
template<bool WM>
__global__ void k_mean_t(const f32x4* __restrict__ x1, const f32x4* __restrict__ x2,
                         f16x4* __restrict__ m1, f16x4* __restrict__ m2,
                         int N1, int N2, float* __restrict__ ws) {
    int b = blockIdx.x, t = threadIdx.x;
    int inp = (b < 512) ? 0 : 1;
    int bl = inp ? (b - 512) : b;
    const f32x4* x = inp ? x2 : x1;
    f16x4* mm = inp ? m2 : m1;
    int N = inp ? N2 : N1;
    int col4 = t & 63, rg = t >> 6;
    f32x4 acc = {0.f, 0.f, 0.f, 0.f};
    for (int r = bl * 4 + rg; r < N; r += 2048) {
        size_t i0 = (size_t)r * 64 + col4;
        f32x4 v = x[i0];
        if (WM) mm[i0] = __builtin_convertvector(v, f16x4);
        acc += v;
    }
    block_reduce_atomic4(acc, t, ws + OFF_SUMREP + inp * (REPS * 256) + (bl & (REPS - 1)) * 256);
}

// hP[inp] += partial of (colsum/N) @ W0 over a 16-row slice of W0.
__global__ void k_hpart(const float* __restrict__ W0, float* __restrict__ ws,
                        int srcOff, int dstOff, int N1, int N2) {
    int inp = blockIdx.x >> 4, g = blockIdx.x & 15;
    int t = threadIdx.x;
    __shared__ float temp[16];
    if (t < 16) {
        const float* src = ws + srcOff + inp * (REPS * 256) + g * 16 + t;
        float s = 0.f;
#pragma unroll
        for (int r = 0; r < REPS; r++) s += src[r * 256];
        temp[t] = s * (1.0f / (float)(inp ? N2 : N1));
    }
    __syncthreads();
    float p = 0.f;
#pragma unroll
    for (int j = 0; j < 16; j++) p += temp[j] * W0[(g * 16 + j) * 256 + t];
    atomicAdd(ws + dstOff + inp * 256 + t, p);
}

// Pass B: s1 = sum_i sigmoid(x_i . h1) * x_i.
// 2 rows per wave (row = 32 lanes x 8 elems); grid 1024 (512/input), stride 4096 rows.
template<typename T>
__global__ void k_att1_t(const T* __restrict__ b1, const T* __restrict__ b2,
                         int N1, int N2, float* __restrict__ ws) {
    int b = blockIdx.x, t = threadIdx.x;
    int inp = (b < 512) ? 0 : 1;
    int bl = inp ? (b - 512) : b;
    const T* x = inp ? b2 : b1;
    int N = inp ? N2 : N1;
    int lane = t & 63, w = t >> 6;
    int half = lane >> 5, l32 = lane & 31;
    f32x8 h1;
#pragma unroll
    for (int j = 0; j < 8; j++) h1[j] = tanhf(ws[OFF_H1P + inp * 256 + l32 * 8 + j]);
    f32x8 acc = {0.f, 0.f, 0.f, 0.f, 0.f, 0.f, 0.f, 0.f};
    int wid = bl * 4 + w;
    int base = wid * 2;
    for (; base + 1 < N; base += 4096) {
        int row = base + half;
        f32x8 v = ld8(x, (size_t)row * 32 + l32);
        float d = dot8(v, h1);
#pragma unroll
        for (int off = 16; off; off >>= 1) d += __shfl_xor(d, off, 64);  // within 32-lane half
        acc += sigmoidf_(d) * v;
    }
    if (base < N && half == 0) {           // odd-N tail (dead for even N)
        f32x8 v = ld8(x, (size_t)base * 32 + l32);
        float d = dot8(v, h1);
#pragma unroll
        for (int off = 16; off; off >>= 1) d += __shfl_xor(d, off, 64);
        acc += sigmoidf_(d) * v;
    }
    block_reduce_atomic8(acc, t, ws + OFF_S1REP + inp * (REPS * 256) + (bl & (REPS - 1)) * 256);
}

// Pass C: o = sum_i att1_i*att2_i*x_i, att2_i = sigmoid(att1_i * (x_i . h2)).
template<typename T>
__global__ void k_att2_t(const T* __restrict__ b1, const T* __restrict__ b2,
                         int N1, int N2, float* __restrict__ ws) {
    int b = blockIdx.x, t = threadIdx.x;
    int inp = (b < 512) ? 0 : 1;
    int bl = inp ? (b - 512) : b;
    const T* x = inp ? b2 : b1;
    int N = inp ? N2 : N1;
    int lane = t & 63, w = t >> 6;
    int half = lane >> 5, l32 = lane & 31;
    f32x8 h1, h2;
#pragma unroll
    for (int j = 0; j < 8; j++) {
        h1[j] = tanhf(ws[OFF_H1P + inp * 256 + l32 * 8 + j]);
        h2[j] = tanhf(ws[OFF_H2P + inp * 256 + l32 * 8 + j]);
    }
    f32x8 acc = {0.f, 0.f, 0.f, 0.f, 0.f, 0.f, 0.f, 0.f};
    int wid = bl * 4 + w;
    int base = wid * 2;
    for (; base + 1 < N; base += 4096) {
        int row = base + half;
        f32x8 v = ld8(x, (size_t)row * 32 + l32);
        float d = dot8(v, h1), e = dot8(v, h2);
#pragma unroll
        for (int off = 16; off; off >>= 1) {
            d += __shfl_xor(d, off, 64); e += __shfl_xor(e, off, 64);
        }
        float a1 = sigmoidf_(d);
        acc += (a1 * sigmoidf_(a1 * e)) * v;
    }
    if (base < N && half == 0) {
        f32x8 v = ld8(x, (size_t)base * 32 + l32);
        float d = dot8(v, h1), e = dot8(v, h2);
#pragma unroll
        for (int off = 16; off; off >>= 1) {
            d += __shfl_xor(d, off, 64); e += __shfl_xor(e, off, 64);
        }
        float a1 = sigmoidf_(d);
        acc += (a1 * sigmoidf_(a1 * e)) * v;
    }
    block_reduce_atomic8(acc, t, ws + OFF_OREP + inp * (REPS * 256) + (bl & (REPS - 1)) * 256);
}

// w_term[f] = g1.W[f].g2 with g=[o,o] folded; o recombined from OREP in-block.
__global__ void __launch_bounds__(256, 4)
k_ntn(const float* __restrict__ W, float* __restrict__ ws) {
    __shared__ __align__(16) float o_l[512];
    int b = blockIdx.x, t = threadIdx.x;
    {
        float s0 = 0.f, s1 = 0.f;
#pragma unroll
        for (int r2 = 0; r2 < REPS; r2++) {
            s0 += ws[OFF_OREP + r2 * 256 + t];
            s1 += ws[OFF_OREP + REPS * 256 + r2 * 256 + t];
        }
        o_l[t] = s0; o_l[256 + t] = s1;
    }
    __syncthreads();
    int lane = t & 63, w = t >> 6;
    f32x4 o2f = ((const f32x4*)(o_l + 256))[lane];
    int g = b * 4 + w;              // global wave id, 2048 waves
    const f32x4* W4 = (const f32x4*)W;
    float wt[4];
    int fidx[4];
#pragma unroll
    for (int u = 0; u < 4; u++) {
        int row = g + u * 2048;     // (f,d) flat, 8192 rows
        const f32x4* q = W4 + (size_t)row * 128 + lane;
        f32x4 m = (q[0] + q[64]) * o2f;
        float p = (m.x + m.y) + (m.z + m.w);
#pragma unroll
        for (int off = 32; off; off >>= 1) p += __shfl_xor(p, off, 64);
        wt[u] = o_l[row & 255] * p;
        fidx[u] = row >> 9;
    }
    if (lane == 0) {
        float* dst = ws + OFF_WTREP + (b & (REPS - 1)) * 16;
#pragma unroll
        for (int u = 0; u < 4; u++) atomicAdd(dst + fidx[u], wt[u]);
    }
}

// v_term + w_term + b -> sigmoid -> 4-layer MLP -> out[0]. o recombined in-block.
__global__ void k_final(const float* __restrict__ V, const float* __restrict__ bb,
                        const float* __restrict__ P0, const float* __restrict__ P1,
                        const float* __restrict__ P2, const float* __restrict__ P3,
                        float* __restrict__ ws, float* __restrict__ out) {
    int t = threadIdx.x;           // 256 threads
    __shared__ float o_l[512];
    {
        float s0 = 0.f, s1 = 0.f;
#pragma unroll
        for (int r2 = 0; r2 < REPS; r2++) {
            s0 += ws[OFF_OREP + r2 * 256 + t];
            s1 += ws[OFF_OREP + REPS * 256 + r2 * 256 + t];
        }
        o_l[t] = s0; o_l[256 + t] = s1;
    }
    __syncthreads();
    int f = t >> 4, j = t & 15;
    float p = 0.f;
    for (int k = j; k < 1024; k += 16) {
        float cv = (k < 512) ? o_l[k & 255] : o_l[256 + (k & 255)];
        p += cv * V[f * 1024 + k];
    }
    __shared__ float red[256];
    __shared__ float sv[16];
    red[t] = p;
    __syncthreads();
    if (t < 16) {
        float v = 0.f;
#pragma unroll
        for (int q = 0; q < 16; q++) v += red[t * 16 + q];
        float wt = 0.f;
#pragma unroll
        for (int r = 0; r < REPS; r++) wt += ws[OFF_WTREP + r * 16 + t];
        sv[t] = sigmoidf_(v + wt + bb[t]);
    }
    __syncthreads();
    if (t == 0) {
        float y0[8], y1[4], y2[2];
#pragma unroll
        for (int i = 0; i < 8; i++) {
            float s = 0.f;
            for (int k = 0; k < 16; k++) s += P0[i * 16 + k] * sv[k];
            y0[i] = sigmoidf_(s);
        }
#pragma unroll
        for (int i = 0; i < 4; i++) {
            float s = 0.f;
            for (int k = 0; k < 8; k++) s += P1[i * 8 + k] * y0[k];
            y1[i] = sigmoidf_(s);
        }
#pragma unroll
        for (int i = 0; i < 2; i++) {
            float s = 0.f;
            for (int k = 0; k < 4; k++) s += P2[i * 4 + k] * y1[k];
            y2[i] = sigmoidf_(s);
        }
        out[0] = sigmoidf_(P3[0] * y2[0] + P3[1] * y2[1]);
    }
}

extern "C" void kernel_launch(void* const* d_in, const int* in_sizes, int n_in,
                              void* d_out, int out_size, void* d_ws, size_t ws_size,
                              hipStream_t stream) {
    const float* x1 = (const float*)d_in[0];
    const float* x2 = (const float*)d_in[1];
    const float* W0 = (const float*)d_in[2];
    const float* V  = (const float*)d_in[3];
    const float* W  = (const float*)d_in[4];
    const float* b  = (const float*)d_in[5];
    const float* P0 = (const float*)d_in[6];
    const float* P1 = (const float*)d_in[7];
    const float* P2 = (const float*)d_in[8];
    const float* P3 = (const float*)d_in[9];
    float* ws  = (float*)d_ws;
    float* out = (float*)d_out;
    int N1 = in_sizes[0] / DD;   // 120000
    int N2 = in_sizes[1] / DD;   // 100000

    const f32x4* x1v = (const f32x4*)x1;
    const f32x4* x2v = (const f32x4*)x2;
    f16x4* m1 = (f16x4*)((char*)d_ws + MIRROR_OFF_BYTES);
    f16x4* m2 = m1 + (size_t)N1 * 64;
    size_t need = (size_t)MIRROR_OFF_BYTES + ((size_t)N1 + N2) * DD * sizeof(_Float16);
    bool use_mirror = ws_size >= need;

    k_zero <<<55, 256, 0, stream>>>(ws);
    if (use_mirror) {
        k_mean_t<true>  <<<1024, 256, 0, stream>>>(x1v, x2v, m1, m2, N1, N2, ws);
        k_hpart         <<<32,   256, 0, stream>>>(W0, ws, OFF_SUMREP, OFF_H1P, N1, N2);
        k_att1_t<f16x8> <<<1024, 256, 0, stream>>>((const f16x8*)m1, (const f16x8*)m2, N1, N2, ws);
        k_hpart         <<<32,   256, 0, stream>>>(W0, ws, OFF_S1REP, OFF_H2P, N1, N2);
        k_att2_t<f16x8> <<<1024, 256, 0, stream>>>((const f16x8*)m1, (const f16x8*)m2, N1, N2, ws);
    } else {
        k_mean_t<false> <<<1024, 256, 0, stream>>>(x1v, x2v, nullptr, nullptr, N1, N2, ws);
        k_hpart         <<<32,   256, 0, stream>>>(W0, ws, OFF_SUMREP, OFF_H1P, N1, N2);
        k_att1_t<f32x8> <<<1024, 256, 0, stream>>>((const f32x8*)x1, (const f32x8*)x2, N1, N2, ws);
        k_hpart         <<<32,   256, 0, stream>>>(W0, ws, OFF_S1REP, OFF_H2P, N1, N2);
        k_att2_t<f32x8> <<<1024, 256, 0, stream>>>((const f32x8*)x1, (const f32x8*)x2, N1, N2, ws);
    }
    k_ntn  <<<512, 256, 0, stream>>>(W, ws);
    k_final<<<1,   256, 0, stream>>>(V, b, P0, P1, P2, P3, ws, out);
}